// Round 13
// baseline (4878.508 us; speedup 1.0000x reference)
//
#include <hip/hip_runtime.h>

// LSTM stack: B=64, T=256, N=M=1024, L=2.
// Persistent cooperative kernel: 256 WGs (1/CU), 1024 threads (16 waves).
// Mat-paired wave groups (dedup h0 reads):
//   group A (waves 0-7):  reads h0 once -> MFMA Wh0 (l0 acc0) + Wx1 (l1 acc1)
//   group B (waves 8-15): x from regs (prefetched across barrier) + h1
//                         -> Wx0 (acc0) + Wh1 (acc1)
// h state in 32-slot RING buffers (fresh address per step => no stale caches;
// leader L2-inv only at ring wrap, every 32 steps).
// h stores: relaxed agent atomic stores (write-through to LLC).
// Barrier: EXACT r10 scheme (passed): 32-leaf tree (8 WGs/leaf) -> root; last
// root arriver broadcasts 8 per-XCD release lines; pollers poll their XCD line.
// NEW vs r10: B-waves issue next-step x prefetch AFTER their h/out stores and
// drain with vmcnt(17) at the barrier — in-order vmcnt retirement means the
// older h-store is complete while the 16 x loads stay in flight across the
// barrier (x is read-only; stale cache copies of x are still correct).

#define T_STEPS 256
#define B_SZ 64
#define M_SZ 1024
#define N_SZ 1024
#define G4M 4096
#define BM 65536                       // B*M
#define RING 32
#define OUTS ((size_t)16777216)        // B*T*M

typedef short short8 __attribute__((ext_vector_type(8)));
typedef float f32x4 __attribute__((ext_vector_type(4)));

static __device__ __forceinline__ unsigned short f2bf(float f) {
  union { float f; unsigned int u; } v; v.f = f;
  unsigned int u = v.u;
  unsigned int r = (u + 0x7FFFu + ((u >> 16) & 1u)) >> 16;
  return (unsigned short)r;
}

static __device__ __forceinline__ float sigf(float x) {
  return 1.f / (1.f + __expf(-x));
}
static __device__ __forceinline__ float tanhfast(float x) {
  return 2.f / (1.f + __expf(-2.f * x)) - 1.f;
}

static __device__ __forceinline__ short8 ld16(const unsigned short* p) {
  return *reinterpret_cast<const short8*>(p);
}

// write-through 16B store (out buffer only; never re-read on device)
static __device__ __forceinline__ void store_wt16(void* p, f32x4 v) {
  asm volatile("global_store_dwordx4 %0, %1, off sc0 sc1" :: "v"(p), "v"(v) : "memory");
}

static __device__ __forceinline__ int xcc_id() {
  int v;
  asm volatile("s_getreg_b32 %0, hwreg(HW_REG_XCC_ID)" : "=s"(v));
  return v & 7;
}

__global__ void convert_x_kernel(const float* __restrict__ x,
                                 unsigned short* __restrict__ xb, int n4) {
  int i = blockIdx.x * blockDim.x + threadIdx.x;
  int stride = gridDim.x * blockDim.x;
  for (; i < n4; i += stride) {
    float4 v = reinterpret_cast<const float4*>(x)[i];
    ushort4 o;
    o.x = f2bf(v.x); o.y = f2bf(v.y); o.z = f2bf(v.z); o.w = f2bf(v.w);
    reinterpret_cast<ushort4*>(xb)[i] = o;
  }
}

__global__ void init_h_kernel(const float* __restrict__ h,
                              unsigned short* __restrict__ h0r,
                              unsigned short* __restrict__ h1r) {
  int i = blockIdx.x * blockDim.x + threadIdx.x;  // 0..65535
  h0r[(size_t)(RING - 1) * BM + i] = f2bf(h[i]);      // layer0 reads slot 31 at k=0
  h1r[i]                           = f2bf(h[BM + i]); // layer1 reads slot 0 at k=1
}

// bar slots (64B each): leaf[0..31]=0-31, root=32, rel[xcd]=34+x,
// relB[xcd]=42+x, claim[xcd]=50+x
__global__ __launch_bounds__(1024, 4) void lstm_persistent(
    const unsigned short* __restrict__ xb,   // [B][T][N] bf16 (cached)
    const float* __restrict__ c_in,          // [L][B][M]
    const float* __restrict__ Wx,            // [L][4M][N]
    const float* __restrict__ Wh,            // [L][4M][M]
    const float* __restrict__ bias,          // [L][4M]
    float* __restrict__ out,                 // outs | h_last | c_last
    unsigned short* __restrict__ h0r,        // [RING][B][M] bf16
    unsigned short* __restrict__ h1r,        // [RING][B][M] bf16
    int* bar) {
  __shared__ short8 sW[4][32][64];   // 128 KiB fragment-packed weights
  __shared__ f32x4 red1[12][64];     // 12 KiB l0 partials
  __shared__ f32x4 red2[12][64];     // 12 KiB l1 partials

  const int cu = blockIdx.x;
  const int tid = threadIdx.x;
  const int lane = tid & 63;
  const int w = tid >> 6;        // 0..15
  const bool grpA = (w < 8);
  const int kh = (w >> 2) & 1;   // k-half
  const int bt = w & 3;          // batch tile
  const int q = lane >> 4;
  const int bl = lane & 15;
  const int bg = bt * 16 + bl;
  const int m0 = cu * 4;
  const int xcd = xcc_id();

  // ---- stage weights (once) ----
  const float* gbase[4] = { Wx, Wh, Wx + (size_t)G4M * N_SZ, Wh + (size_t)G4M * M_SZ };
  for (int mat = 0; mat < 4; ++mat) {
    const float* base = gbase[mat];
    for (int s = tid; s < 32 * 64; s += 1024) {
      int kt = s >> 6, ls = s & 63;
      int r = ls & 15;
      int k0 = kt * 32 + (ls >> 4) * 8;
      int j = (r >> 2) * 1024 + m0 + (r & 3);
      const float* src = base + (size_t)j * 1024 + k0;
      float4 a = reinterpret_cast<const float4*>(src)[0];
      float4 b2 = reinterpret_cast<const float4*>(src)[1];
      short8 wv;
      wv[0] = (short)f2bf(a.x); wv[1] = (short)f2bf(a.y);
      wv[2] = (short)f2bf(a.z); wv[3] = (short)f2bf(a.w);
      wv[4] = (short)f2bf(b2.x); wv[5] = (short)f2bf(b2.y);
      wv[6] = (short)f2bf(b2.z); wv[7] = (short)f2bf(b2.w);
      sW[mat][kt][ls] = wv;
    }
  }

  // ---- static per-XCD leader election (once) ----
  bool leader = false;
  if (tid == 0) {
    int expected = 0;
    leader = __hip_atomic_compare_exchange_strong(
        bar + 16 * (50 + xcd), &expected, cu + 1, __ATOMIC_RELAXED,
        __ATOMIC_RELAXED, __HIP_MEMORY_SCOPE_AGENT);
  }
  __syncthreads();

  // ---- pointwise-owner state ----
  float c_st[4] = {0.f, 0.f, 0.f, 0.f};
  float bs[4] = {0.f, 0.f, 0.f, 0.f};
  if (kh == 0) {
    const int layer = grpA ? 0 : 1;
#pragma unroll
    for (int e = 0; e < 4; ++e) {
      c_st[e] = c_in[layer * BM + bg * M_SZ + m0 + e];
      bs[e] = bias[layer * G4M + q * 1024 + m0 + e];
    }
  }

  const int ko = q * 8;
  const int ktb = kh * 16;

  // B waves: full x[0] register prefetch (x is read-only; caches fine)
  short8 pfx[16];
  if (!grpA) {
    const unsigned short* px = xb + (size_t)bg * T_STEPS * N_SZ;
#pragma unroll
    for (int j = 0; j < 16; ++j) pfx[j] = ld16(px + (ktb + j) * 32 + ko);
  }

  for (int k = 0; k <= T_STEPS; ++k) {
    const int rs = (k + RING - 1) & (RING - 1);  // read slot (state from k-1)
    const int wslot = k & (RING - 1);            // write slot
    f32x4 acc0 = { 0.f, 0.f, 0.f, 0.f };   // l0-product partial
    f32x4 acc1 = { 0.f, 0.f, 0.f, 0.f };   // l1-product partial
    if (kh == 0) {
      if (grpA) { acc0[0] = bs[0]; acc0[1] = bs[1]; acc0[2] = bs[2]; acc0[3] = bs[3]; }
      else      { acc1[0] = bs[0]; acc1[1] = bs[1]; acc1[2] = bs[2]; acc1[3] = bs[3]; }
    }

    if (grpA) {
      // ---- A: read h0 once, all 16 loads in flight; Wh0->acc0, Wx1->acc1 ----
      const unsigned short* ph0 = h0r + (size_t)rs * BM + (size_t)bg * M_SZ;
      short8 a[16];
#pragma unroll
      for (int j = 0; j < 16; ++j) a[j] = ld16(ph0 + (ktb + j) * 32 + ko);
      asm volatile("" ::
        "v"(a[0]), "v"(a[1]), "v"(a[2]), "v"(a[3]),
        "v"(a[4]), "v"(a[5]), "v"(a[6]), "v"(a[7]),
        "v"(a[8]), "v"(a[9]), "v"(a[10]), "v"(a[11]),
        "v"(a[12]), "v"(a[13]), "v"(a[14]), "v"(a[15]));
      __builtin_amdgcn_sched_barrier(0);
#pragma unroll
      for (int j = 0; j < 16; ++j) {
        int kt = ktb + j;
        acc0 = __builtin_amdgcn_mfma_f32_16x16x32_bf16(sW[1][kt][lane], a[j], acc0, 0, 0, 0);
        acc1 = __builtin_amdgcn_mfma_f32_16x16x32_bf16(sW[2][kt][lane], a[j], acc1, 0, 0, 0);
      }
    } else {
      // ---- B: h1 loads (16 in flight); x from prefetch regs ----
      const unsigned short* ph1 = h1r + (size_t)rs * BM + (size_t)bg * M_SZ;
      short8 fh[16];
#pragma unroll
      for (int j = 0; j < 16; ++j) fh[j] = ld16(ph1 + (ktb + j) * 32 + ko);
      asm volatile("" ::
        "v"(fh[0]), "v"(fh[1]), "v"(fh[2]), "v"(fh[3]),
        "v"(fh[4]), "v"(fh[5]), "v"(fh[6]), "v"(fh[7]),
        "v"(fh[8]), "v"(fh[9]), "v"(fh[10]), "v"(fh[11]),
        "v"(fh[12]), "v"(fh[13]), "v"(fh[14]), "v"(fh[15]));
      __builtin_amdgcn_sched_barrier(0);
#pragma unroll
      for (int j = 0; j < 16; ++j) {
        int kt = ktb + j;
        acc0 = __builtin_amdgcn_mfma_f32_16x16x32_bf16(sW[0][kt][lane], pfx[j], acc0, 0, 0, 0);
        acc1 = __builtin_amdgcn_mfma_f32_16x16x32_bf16(sW[3][kt][lane], fh[j], acc1, 0, 0, 0);
      }
    }

    // ---- partial-sum exchange (LDS-only sync) ----
    if (w < 4)            { red2[bt][lane] = acc1; }
    else if (w < 8)       { red1[bt][lane] = acc0; red2[4 + bt][lane] = acc1; }
    else if (w < 12)      { red1[4 + bt][lane] = acc0; }
    else                  { red1[8 + bt][lane] = acc0; red2[8 + bt][lane] = acc1; }
    asm volatile("s_waitcnt lgkmcnt(0)" ::: "memory");
    __builtin_amdgcn_s_barrier();
    __builtin_amdgcn_sched_barrier(0);

    // ---- layer-0 pointwise (waves 0..3), t = k ----
    if (w < 4 && k < T_STEPS) {
      f32x4 tot = acc0 + red1[bt][lane] + red1[4 + bt][lane] + red1[8 + bt][lane];
      float hv[4];
#pragma unroll
      for (int e = 0; e < 4; ++e) {
        float ge_i = __shfl(tot[e], bl);
        float ge_f = __shfl(tot[e], bl + 16);
        float ge_g = __shfl(tot[e], bl + 32);
        float ge_o = __shfl(tot[e], bl + 48);
        float gi = sigf(ge_i), gf = sigf(ge_f);
        float gg = tanhfast(ge_g), go = sigf(ge_o);
        float c = gf * c_st[e] + gi * gg;
        c_st[e] = c;
        hv[e] = go * tanhfast(c);
      }
      if (q == 0) {
        unsigned short* hdst = h0r + (size_t)wslot * BM + (size_t)bg * M_SZ + m0;
        unsigned long long hb =
            (unsigned long long)f2bf(hv[0]) |
            ((unsigned long long)f2bf(hv[1]) << 16) |
            ((unsigned long long)f2bf(hv[2]) << 32) |
            ((unsigned long long)f2bf(hv[3]) << 48);
        __hip_atomic_store((unsigned long long*)hdst, hb, __ATOMIC_RELAXED,
                           __HIP_MEMORY_SCOPE_AGENT);
        if (k == T_STEPS - 1) {
          f32x4 hf = { hv[0], hv[1], hv[2], hv[3] };
          f32x4 cf = { c_st[0], c_st[1], c_st[2], c_st[3] };
          store_wt16(out + OUTS + (size_t)bg * M_SZ + m0, hf);
          store_wt16(out + OUTS + 2 * (size_t)BM + (size_t)bg * M_SZ + m0, cf);
        }
      }
    }

    // ---- layer-1 pointwise (waves 8..11), t = k-1 ----
    if (w >= 8 && w < 12 && k >= 1) {
      const int t = k - 1;
      f32x4 tot = acc1 + red2[bt][lane] + red2[4 + bt][lane] + red2[8 + bt][lane];
      float hv[4];
#pragma unroll
      for (int e = 0; e < 4; ++e) {
        float ge_i = __shfl(tot[e], bl);
        float ge_f = __shfl(tot[e], bl + 16);
        float ge_g = __shfl(tot[e], bl + 32);
        float ge_o = __shfl(tot[e], bl + 48);
        float gi = sigf(ge_i), gf = sigf(ge_f);
        float gg = tanhfast(ge_g), go = sigf(ge_o);
        float c = gf * c_st[e] + gi * gg;
        c_st[e] = c;
        hv[e] = go * tanhfast(c);
      }
      if (q == 0) {
        unsigned short* hdst = h1r + (size_t)wslot * BM + (size_t)bg * M_SZ + m0;
        unsigned long long hb =
            (unsigned long long)f2bf(hv[0]) |
            ((unsigned long long)f2bf(hv[1]) << 16) |
            ((unsigned long long)f2bf(hv[2]) << 32) |
            ((unsigned long long)f2bf(hv[3]) << 48);
        __hip_atomic_store((unsigned long long*)hdst, hb, __ATOMIC_RELAXED,
                           __HIP_MEMORY_SCOPE_AGENT);
        f32x4 ov = { hv[0], hv[1], hv[2], hv[3] };
        store_wt16(out + ((size_t)bg * T_STEPS + t) * M_SZ + m0, ov);
        if (k == T_STEPS) {
          f32x4 hf = { hv[0], hv[1], hv[2], hv[3] };
          f32x4 cf = { c_st[0], c_st[1], c_st[2], c_st[3] };
          store_wt16(out + OUTS + (size_t)BM + (size_t)bg * M_SZ + m0, hf);
          store_wt16(out + OUTS + 3 * (size_t)BM + (size_t)bg * M_SZ + m0, cf);
        }
      }
    }

    // ---- B waves: issue next-step x prefetch AFTER stores (flies across
    //      the barrier; always 16 loads so the vmcnt(17) count is exact) ----
    if (!grpA && k < T_STEPS) {
      __builtin_amdgcn_sched_barrier(0);   // pin: stores above, prefetch below
      const int tn = (k + 1 < T_STEPS) ? (k + 1) : (T_STEPS - 1);
      const unsigned short* pxn = xb + ((size_t)bg * T_STEPS + tn) * N_SZ;
#pragma unroll
      for (int j = 0; j < 16; ++j) pfx[j] = ld16(pxn + (ktb + j) * 32 + ko);
      asm volatile("" ::
        "v"(pfx[0]), "v"(pfx[1]), "v"(pfx[2]), "v"(pfx[3]),
        "v"(pfx[4]), "v"(pfx[5]), "v"(pfx[6]), "v"(pfx[7]),
        "v"(pfx[8]), "v"(pfx[9]), "v"(pfx[10]), "v"(pfx[11]),
        "v"(pfx[12]), "v"(pfx[13]), "v"(pfx[14]), "v"(pfx[15]));
      __builtin_amdgcn_sched_barrier(0);
    }

    // ---- grid barrier: EXACT r10 scheme (32-leaf tree + broadcast release) ----
    if (k < T_STEPS) {
      const int target = k + 1;
      const bool invstep = ((k & (RING - 1)) == (RING - 1));
      // w<4: drain h0 store fully. w8-11: vmcnt(17) -> with issue order
      // [h store, out store, 16 pfx], in-order retirement guarantees the
      // h store is complete while prefetches stay in flight.
      if (w < 4)
        asm volatile("s_waitcnt vmcnt(0)" ::: "memory");
      else if (w >= 8 && w < 12)
        asm volatile("s_waitcnt vmcnt(17)" ::: "memory");
      __builtin_amdgcn_s_barrier();          // all h stores visible at LLC
      if (tid == 0) {
        int* leaf = bar + 16 * (cu & 31);    // 8 WGs per leaf
        int* root = bar + 16 * 32;
        int prev = __hip_atomic_fetch_add(leaf, 1, __ATOMIC_RELAXED, __HIP_MEMORY_SCOPE_AGENT);
        if ((prev & 7) == 7) {
          int pr2 = __hip_atomic_fetch_add(root, 1, __ATOMIC_RELAXED, __HIP_MEMORY_SCOPE_AGENT);
          if ((pr2 & 31) == 31) {
            // LAST ARRIVER: broadcast release to all 8 XCD lines
#pragma unroll
            for (int xx = 0; xx < 8; ++xx)
              __hip_atomic_store(bar + 16 * (34 + xx), target, __ATOMIC_RELAXED,
                                 __HIP_MEMORY_SCOPE_AGENT);
          }
        }
        int guard = 0;
        int* rel  = bar + 16 * (34 + xcd);
        int* relB = bar + 16 * (42 + xcd);
        if (!invstep) {
          while (__hip_atomic_load(rel, __ATOMIC_RELAXED, __HIP_MEMORY_SCOPE_AGENT) < target) {
            __builtin_amdgcn_s_sleep(1);
            if (++guard > (1 << 20)) break;  // failsafe: wrong answer, not hang
          }
        } else if (leader) {
          while (__hip_atomic_load(rel, __ATOMIC_RELAXED, __HIP_MEMORY_SCOPE_AGENT) < target) {
            __builtin_amdgcn_s_sleep(1);
            if (++guard > (1 << 20)) break;
          }
          asm volatile("buffer_inv sc0 sc1\n\ts_waitcnt vmcnt(0)" ::: "memory");
          __hip_atomic_store(relB, target, __ATOMIC_RELAXED, __HIP_MEMORY_SCOPE_AGENT);
        } else {
          while (__hip_atomic_load(relB, __ATOMIC_RELAXED, __HIP_MEMORY_SCOPE_AGENT) < target) {
            __builtin_amdgcn_s_sleep(1);
            if (++guard > (1 << 20)) break;
          }
          asm volatile("buffer_inv sc0\n\ts_waitcnt vmcnt(0)" ::: "memory");  // L1 only
        }
      }
      __builtin_amdgcn_s_barrier();          // release within WG
      __builtin_amdgcn_sched_barrier(0);     // keep next-step h loads below
    }
  }
}

extern "C" void kernel_launch(void* const* d_in, const int* in_sizes, int n_in,
                              void* d_out, int out_size, void* d_ws, size_t ws_size,
                              hipStream_t stream) {
  (void)in_sizes; (void)n_in; (void)out_size; (void)ws_size;
  const float* x  = (const float*)d_in[0];
  const float* h  = (const float*)d_in[1];
  const float* c  = (const float*)d_in[2];
  const float* Wx = (const float*)d_in[3];
  const float* Wh = (const float*)d_in[4];
  const float* b  = (const float*)d_in[5];
  float* out = (float*)d_out;

  char* ws = (char*)d_ws;
  int* bar = (int*)ws;                              // counter cachelines
  unsigned short* h0r = (unsigned short*)(ws + 4096);
  unsigned short* h1r = (unsigned short*)(ws + 4096 + (size_t)RING * BM * 2);
  unsigned short* xb  = (unsigned short*)(ws + 4096 + (size_t)RING * BM * 4);
  // ws use: 4096 + 2*4MB (h rings) + 32MB (xb) ~= 40 MB

  (void)hipMemsetAsync(ws, 0, 4096, stream);
  convert_x_kernel<<<2048, 256, 0, stream>>>(x, xb, (B_SZ * T_STEPS * N_SZ) / 4);
  init_h_kernel<<<256, 256, 0, stream>>>(h, h0r, h1r);
  lstm_persistent<<<256, 1024, 0, stream>>>(xb, c, Wx, Wh, b, out, h0r, h1r, bar);
}

// Round 15
// 3150.981 us; speedup vs baseline: 1.5483x; 1.5483x over previous
//
#include <hip/hip_runtime.h>

// LSTM stack: B=64, T=256, N=M=1024, L=2 — DECOUPLED LAYER PIPELINES.
// 256 WGs (1/CU), 1024 threads (16 waves). Group g = cu&1:
//   g=0 CUs run layer0 only (8 m-units each, cuL = cu>>1, mbase = cuL*8)
//   g=1 CUs run layer1 only.
// Each group:独立 128-WG leaf-tree barrier (16 leaves x 8), own pace.
// Cross-coupling: layer0 publishes prog0 (completed steps) at its barrier;
// layer1's barrier release also waits prog0 >= k+2 (next step's h0 ready).
// Layer0 waits prog1 >= k-30 before overrunning the 32-slot h0 ring.
// h state in 32-slot rings; relaxed agent WT stores; per-(group,XCD) leader
// L2-inv at ring wrap (k%32==31). Wave roles per CU: src=w>>3 (0: A-input
// = x (g0) / lagged h0 (g1); 1: R-input = own h), kh=(w>>2)&1, bt=w&3.
// Each wave: 16 frag loads, 32 MFMAs (feeds mg0+mg1 weight rows).
// Owners (w<4) reduce via LDS, do pointwise for mg0+mg1, store h/out.

#define T_STEPS 256
#define B_SZ 64
#define M_SZ 1024
#define N_SZ 1024
#define G4M 4096
#define BM 65536                       // B*M
#define RING 32
#define OUTS ((size_t)16777216)        // B*T*M

typedef short short8 __attribute__((ext_vector_type(8)));
typedef float f32x4 __attribute__((ext_vector_type(4)));

static __device__ __forceinline__ unsigned short f2bf(float f) {
  union { float f; unsigned int u; } v; v.f = f;
  unsigned int u = v.u;
  unsigned int r = (u + 0x7FFFu + ((u >> 16) & 1u)) >> 16;
  return (unsigned short)r;
}

static __device__ __forceinline__ float sigf(float x) {
  return 1.f / (1.f + __expf(-x));
}
static __device__ __forceinline__ float tanhfast(float x) {
  return 2.f / (1.f + __expf(-2.f * x)) - 1.f;
}

static __device__ __forceinline__ short8 ld16(const unsigned short* p) {
  return *reinterpret_cast<const short8*>(p);
}

// write-through 16B store (out buffer only; never re-read on device)
static __device__ __forceinline__ void store_wt16(void* p, f32x4 v) {
  asm volatile("global_store_dwordx4 %0, %1, off sc0 sc1" :: "v"(p), "v"(v) : "memory");
}

static __device__ __forceinline__ int xcc_id() {
  int v;
  asm volatile("s_getreg_b32 %0, hwreg(HW_REG_XCC_ID)" : "=s"(v));
  return v & 7;
}

__global__ void convert_x_kernel(const float* __restrict__ x,
                                 unsigned short* __restrict__ xb, int n4) {
  int i = blockIdx.x * blockDim.x + threadIdx.x;
  int stride = gridDim.x * blockDim.x;
  for (; i < n4; i += stride) {
    float4 v = reinterpret_cast<const float4*>(x)[i];
    ushort4 o;
    o.x = f2bf(v.x); o.y = f2bf(v.y); o.z = f2bf(v.z); o.w = f2bf(v.w);
    reinterpret_cast<ushort4*>(xb)[i] = o;
  }
}

__global__ void init_h_kernel(const float* __restrict__ h,
                              unsigned short* __restrict__ h0r,
                              unsigned short* __restrict__ h1r) {
  int i = blockIdx.x * blockDim.x + threadIdx.x;  // 0..65535
  h0r[(size_t)(RING - 1) * BM + i] = f2bf(h[i]);       // l0 t=0 reads rs=31
  h1r[(size_t)(RING - 1) * BM + i] = f2bf(h[BM + i]);  // l1 t=0 reads rs=31
}

// bar 64B slots: leaf g0:0-15, g1:16-31; root 32+g; rel 34+g*8+xcd;
// relB 50+g*8+xcd; claim 66+g*8+xcd; prog 82+g.
__global__ __launch_bounds__(1024, 4) void lstm_persistent(
    const unsigned short* __restrict__ xb,   // [B][T][N] bf16 (cached)
    const float* __restrict__ c_in,          // [L][B][M]
    const float* __restrict__ Wx,            // [L][4M][N]
    const float* __restrict__ Wh,            // [L][4M][M]
    const float* __restrict__ bias,          // [L][4M]
    float* __restrict__ out,                 // outs | h_last | c_last
    unsigned short* __restrict__ h0r,        // [RING][B][M] bf16
    unsigned short* __restrict__ h1r,        // [RING][B][M] bf16
    int* bar) {
  __shared__ short8 sW[2][2][32][64];  // [mat X/H][mg][kt][lane] 128 KiB
  __shared__ f32x4 red1[12][64];       // mg0 partials
  __shared__ f32x4 red2[12][64];       // mg1 partials

  const int cu = blockIdx.x;
  const int tid = threadIdx.x;
  const int lane = tid & 63;
  const int w = tid >> 6;        // 0..15
  const int g = cu & 1;          // layer group
  const int cuL = cu >> 1;       // 0..127 within group
  const int src = w >> 3;        // 0: A-input, 1: R-input
  const int kh = (w >> 2) & 1;
  const int bt = w & 3;
  const int q = lane >> 4;
  const int bl = lane & 15;
  const int bg = bt * 16 + bl;
  const int mbase = cuL * 8;
  const int xcd = xcc_id();
  const bool owner = (w < 4);

  unsigned short* hr_own = g ? h1r : h0r;

  // ---- stage weights (once): this layer's Wx + Wh for 32 gate rows ----
  {
    const float* baseX = Wx + (size_t)g * G4M * N_SZ;
    const float* baseH = Wh + (size_t)g * G4M * M_SZ;
#pragma unroll
    for (int mat = 0; mat < 2; ++mat) {
      const float* base = mat ? baseH : baseX;
#pragma unroll
      for (int mg = 0; mg < 2; ++mg) {
        for (int s = tid; s < 32 * 64; s += 1024) {
          int kt = s >> 6, ls = s & 63;
          int r = ls & 15;
          int k0 = kt * 32 + (ls >> 4) * 8;
          int j = (r >> 2) * 1024 + mbase + mg * 4 + (r & 3);
          const float* srcp = base + (size_t)j * 1024 + k0;
          float4 a = reinterpret_cast<const float4*>(srcp)[0];
          float4 b2 = reinterpret_cast<const float4*>(srcp)[1];
          short8 wv;
          wv[0] = (short)f2bf(a.x); wv[1] = (short)f2bf(a.y);
          wv[2] = (short)f2bf(a.z); wv[3] = (short)f2bf(a.w);
          wv[4] = (short)f2bf(b2.x); wv[5] = (short)f2bf(b2.y);
          wv[6] = (short)f2bf(b2.z); wv[7] = (short)f2bf(b2.w);
          sW[mat][mg][kt][ls] = wv;
        }
      }
    }
  }

  // ---- per-(group,XCD) leader election (once) ----
  bool leader = false;
  if (tid == 0) {
    int expected = 0;
    leader = __hip_atomic_compare_exchange_strong(
        bar + 16 * (66 + g * 8 + xcd), &expected, cu + 1, __ATOMIC_RELAXED,
        __ATOMIC_RELAXED, __HIP_MEMORY_SCOPE_AGENT);
  }
  __syncthreads();

  // ---- owner state: c and bias for mg0, mg1 ----
  float c_st[2][4] = {{0.f,0.f,0.f,0.f},{0.f,0.f,0.f,0.f}};
  float bs[2][4] = {{0.f,0.f,0.f,0.f},{0.f,0.f,0.f,0.f}};
  if (owner) {
#pragma unroll
    for (int mg = 0; mg < 2; ++mg)
#pragma unroll
      for (int e = 0; e < 4; ++e) {
        c_st[mg][e] = c_in[g * BM + bg * M_SZ + mbase + mg * 4 + e];
        bs[mg][e] = bias[g * G4M + q * 1024 + mbase + mg * 4 + e];
      }
  }

  const int ko = q * 8;
  const int ktb = kh * 16;
  int* prog0 = bar + 16 * 82;
  int* prog1 = bar + 16 * 83;

  // layer1: wait for layer0's step 0 before starting
  if (g == 1 && tid == 0) {
    int guard = 0;
    while (__hip_atomic_load(prog0, __ATOMIC_RELAXED, __HIP_MEMORY_SCOPE_AGENT) < 1) {
      __builtin_amdgcn_s_sleep(1);
      if (++guard > (1 << 22)) break;
    }
  }
  __syncthreads();

  for (int k = 0; k < T_STEPS; ++k) {
    const int rs = (k + RING - 1) & (RING - 1);
    const int wslot = k & (RING - 1);

    // ---- input pointer for this wave ----
    const unsigned short* ip;
    if (src == 0) {
      ip = g ? (h0r + (size_t)wslot * BM + (size_t)bg * M_SZ)         // h0[t=k]
             : (xb + ((size_t)bg * T_STEPS + k) * N_SZ);              // x[t=k]
    } else {
      ip = hr_own + (size_t)rs * BM + (size_t)bg * M_SZ;              // h[t-1]
    }

    f32x4 acc0 = { 0.f, 0.f, 0.f, 0.f };
    f32x4 acc1 = { 0.f, 0.f, 0.f, 0.f };
    if (owner) {
#pragma unroll
      for (int e = 0; e < 4; ++e) { acc0[e] = bs[0][e]; acc1[e] = bs[1][e]; }
    }

    // ---- 16 fragment loads, all in flight; 32 MFMAs (mg0 + mg1) ----
    short8 f[16];
#pragma unroll
    for (int j = 0; j < 16; ++j) f[j] = ld16(ip + (ktb + j) * 32 + ko);
    asm volatile("" ::
      "v"(f[0]), "v"(f[1]), "v"(f[2]), "v"(f[3]),
      "v"(f[4]), "v"(f[5]), "v"(f[6]), "v"(f[7]),
      "v"(f[8]), "v"(f[9]), "v"(f[10]), "v"(f[11]),
      "v"(f[12]), "v"(f[13]), "v"(f[14]), "v"(f[15]));
    __builtin_amdgcn_sched_barrier(0);
#pragma unroll
    for (int j = 0; j < 16; ++j) {
      int kt = ktb + j;
      acc0 = __builtin_amdgcn_mfma_f32_16x16x32_bf16(sW[src][0][kt][lane], f[j], acc0, 0, 0, 0);
      acc1 = __builtin_amdgcn_mfma_f32_16x16x32_bf16(sW[src][1][kt][lane], f[j], acc1, 0, 0, 0);
    }

    // ---- reduce partials (writers: w4-15) ----
    if (!owner) {
      int idx = (w >> 2) - 1;          // 0,1,2
      red1[idx * 4 + bt][lane] = acc0;
      red2[idx * 4 + bt][lane] = acc1;
    }
    asm volatile("s_waitcnt lgkmcnt(0)" ::: "memory");
    __builtin_amdgcn_s_barrier();
    __builtin_amdgcn_sched_barrier(0);

    // ---- owners: pointwise for mg0, mg1 ----
    if (owner) {
      f32x4 tot[2];
      tot[0] = acc0 + red1[bt][lane] + red1[4 + bt][lane] + red1[8 + bt][lane];
      tot[1] = acc1 + red2[bt][lane] + red2[4 + bt][lane] + red2[8 + bt][lane];
      float hv[2][4];
#pragma unroll
      for (int mg = 0; mg < 2; ++mg) {
#pragma unroll
        for (int e = 0; e < 4; ++e) {
          float ge_i = __shfl(tot[mg][e], bl);
          float ge_f = __shfl(tot[mg][e], bl + 16);
          float ge_g = __shfl(tot[mg][e], bl + 32);
          float ge_o = __shfl(tot[mg][e], bl + 48);
          float gi = sigf(ge_i), gf = sigf(ge_f);
          float gg = tanhfast(ge_g), go = sigf(ge_o);
          float c = gf * c_st[mg][e] + gi * gg;
          c_st[mg][e] = c;
          hv[mg][e] = go * tanhfast(c);
        }
      }
      if (q == 0) {
#pragma unroll
        for (int mg = 0; mg < 2; ++mg) {
          unsigned short* hdst = hr_own + (size_t)wslot * BM +
                                 (size_t)bg * M_SZ + mbase + mg * 4;
          unsigned long long hb =
              (unsigned long long)f2bf(hv[mg][0]) |
              ((unsigned long long)f2bf(hv[mg][1]) << 16) |
              ((unsigned long long)f2bf(hv[mg][2]) << 32) |
              ((unsigned long long)f2bf(hv[mg][3]) << 48);
          __hip_atomic_store((unsigned long long*)hdst, hb, __ATOMIC_RELAXED,
                             __HIP_MEMORY_SCOPE_AGENT);
          if (g == 1) {
            f32x4 ov = { hv[mg][0], hv[mg][1], hv[mg][2], hv[mg][3] };
            store_wt16(out + ((size_t)bg * T_STEPS + k) * M_SZ + mbase + mg * 4, ov);
          }
          if (k == T_STEPS - 1) {
            f32x4 hf = { hv[mg][0], hv[mg][1], hv[mg][2], hv[mg][3] };
            f32x4 cf = { c_st[mg][0], c_st[mg][1], c_st[mg][2], c_st[mg][3] };
            store_wt16(out + OUTS + (size_t)g * BM + (size_t)bg * M_SZ + mbase + mg * 4, hf);
            store_wt16(out + OUTS + 2 * (size_t)BM + (size_t)g * BM +
                       (size_t)bg * M_SZ + mbase + mg * 4, cf);
          }
        }
      }
    }

    // ---- group barrier + progress publication + cross-group gates ----
    {
      const int target = k + 1;
      const bool invstep = ((k & (RING - 1)) == (RING - 1));
      if (owner)
        asm volatile("s_waitcnt vmcnt(0)" ::: "memory");
      __builtin_amdgcn_s_barrier();          // group's h stores visible at LLC
      if (tid == 0) {
        int* leaf = bar + 16 * (g * 16 + (cuL & 15));   // 8 WGs per leaf
        int* root = bar + 16 * (32 + g);
        int prev = __hip_atomic_fetch_add(leaf, 1, __ATOMIC_RELAXED, __HIP_MEMORY_SCOPE_AGENT);
        if ((prev & 7) == 7) {
          int pr2 = __hip_atomic_fetch_add(root, 1, __ATOMIC_RELAXED, __HIP_MEMORY_SCOPE_AGENT);
          if ((pr2 & 15) == 15) {
            // last arriver of this group: publish progress + release
            __hip_atomic_store(bar + 16 * (82 + g), target, __ATOMIC_RELAXED,
                               __HIP_MEMORY_SCOPE_AGENT);
#pragma unroll
            for (int xx = 0; xx < 8; ++xx)
              __hip_atomic_store(bar + 16 * (34 + g * 8 + xx), target,
                                 __ATOMIC_RELAXED, __HIP_MEMORY_SCOPE_AGENT);
          }
        }
        int guard = 0;
        int* rel  = bar + 16 * (34 + g * 8 + xcd);
        int* relB = bar + 16 * (50 + g * 8 + xcd);
        while (__hip_atomic_load(rel, __ATOMIC_RELAXED, __HIP_MEMORY_SCOPE_AGENT) < target) {
          __builtin_amdgcn_s_sleep(1);
          if (++guard > (1 << 22)) break;    // failsafe: wrong answer, not hang
        }
        // cross-group gates for the UPCOMING step (k+1)
        if (g == 1 && k + 1 < T_STEPS) {
          int need = (k + 2 < T_STEPS + 1) ? (k + 2) : T_STEPS;
          guard = 0;
          while (__hip_atomic_load(prog0, __ATOMIC_RELAXED, __HIP_MEMORY_SCOPE_AGENT) < need) {
            __builtin_amdgcn_s_sleep(1);
            if (++guard > (1 << 22)) break;
          }
        } else if (g == 0 && k + 1 >= RING && k + 1 < T_STEPS) {
          int need = k - 30;                 // layer1 must have consumed old slot
          guard = 0;
          while (__hip_atomic_load(prog1, __ATOMIC_RELAXED, __HIP_MEMORY_SCOPE_AGENT) < need) {
            __builtin_amdgcn_s_sleep(1);
            if (++guard > (1 << 22)) break;
          }
        }
        if (invstep) {
          if (leader) {
            asm volatile("buffer_inv sc0 sc1\n\ts_waitcnt vmcnt(0)" ::: "memory");
            __hip_atomic_store(relB, target, __ATOMIC_RELAXED, __HIP_MEMORY_SCOPE_AGENT);
          } else {
            guard = 0;
            while (__hip_atomic_load(relB, __ATOMIC_RELAXED, __HIP_MEMORY_SCOPE_AGENT) < target) {
              __builtin_amdgcn_s_sleep(1);
              if (++guard > (1 << 22)) break;
            }
            asm volatile("buffer_inv sc0\n\ts_waitcnt vmcnt(0)" ::: "memory");
          }
        }
      }
      __builtin_amdgcn_s_barrier();          // release within WG
      __builtin_amdgcn_sched_barrier(0);
    }
  }
}

extern "C" void kernel_launch(void* const* d_in, const int* in_sizes, int n_in,
                              void* d_out, int out_size, void* d_ws, size_t ws_size,
                              hipStream_t stream) {
  (void)in_sizes; (void)n_in; (void)out_size; (void)ws_size;
  const float* x  = (const float*)d_in[0];
  const float* h  = (const float*)d_in[1];
  const float* c  = (const float*)d_in[2];
  const float* Wx = (const float*)d_in[3];
  const float* Wh = (const float*)d_in[4];
  const float* b  = (const float*)d_in[5];
  float* out = (float*)d_out;

  char* ws = (char*)d_ws;
  int* bar = (int*)ws;                              // counter cachelines (<8KB)
  unsigned short* h0r = (unsigned short*)(ws + 8192);
  unsigned short* h1r = (unsigned short*)(ws + 8192 + (size_t)RING * BM * 2);
  unsigned short* xb  = (unsigned short*)(ws + 8192 + (size_t)RING * BM * 4);
  // ws use: 8 KB + 2*4 MB (h rings) + 32 MB (xb) ~= 40 MB

  (void)hipMemsetAsync(ws, 0, 8192, stream);
  convert_x_kernel<<<2048, 256, 0, stream>>>(x, xb, (B_SZ * T_STEPS * N_SZ) / 4);
  init_h_kernel<<<256, 256, 0, stream>>>(h, h0r, h1r);
  lstm_persistent<<<256, 1024, 0, stream>>>(xb, c, Wx, Wh, b, out, h0r, h1r, bar);
}

// Round 16
// 3121.470 us; speedup vs baseline: 1.5629x; 1.0095x over previous
//
#include <hip/hip_runtime.h>

// LSTM stack: B=64, T=256, N=M=1024, L=2 — DECOUPLED LAYER PIPELINES (r15 base).
// 256 WGs (1/CU), 1024 threads (16 waves). Group g = cu&1:
//   g=0 CUs run layer0 (8 m-units each, cuL = cu>>1), g=1 CUs run layer1.
// Per-group 128-WG leaf-tree barrier (16 leaves x 8 -> root 16); last root
// arriver publishes prog[g] and broadcasts 8 per-XCD release lines.
// Cross-coupling: l1's barrier also waits prog0 >= k+2; l0 waits prog1 >= k-62
// before overwriting ring slots (RING=64). Leader L2-inv at ring wrap only.
// h stores: relaxed agent WT atomics.
// r16 deltas vs r15: (1) g1 owners drain vmcnt(1) (HBM out-store flies across
// the barrier; in-order vmcnt => h store retired); (2) g0 waves 4-7 issue ONE
// dword touch per lane covering x[t+1] (XCD-sliced by cuL&3) + vmcnt(0) drain
// before barrier -> x lines L2-warm at next release; (3) RING 32->64.

#define T_STEPS 256
#define B_SZ 64
#define M_SZ 1024
#define N_SZ 1024
#define G4M 4096
#define BM 65536                       // B*M
#define RING 64
#define OUTS ((size_t)16777216)        // B*T*M

typedef short short8 __attribute__((ext_vector_type(8)));
typedef float f32x4 __attribute__((ext_vector_type(4)));

static __device__ __forceinline__ unsigned short f2bf(float f) {
  union { float f; unsigned int u; } v; v.f = f;
  unsigned int u = v.u;
  unsigned int r = (u + 0x7FFFu + ((u >> 16) & 1u)) >> 16;
  return (unsigned short)r;
}

static __device__ __forceinline__ float sigf(float x) {
  return 1.f / (1.f + __expf(-x));
}
static __device__ __forceinline__ float tanhfast(float x) {
  return 2.f / (1.f + __expf(-2.f * x)) - 1.f;
}

static __device__ __forceinline__ short8 ld16(const unsigned short* p) {
  return *reinterpret_cast<const short8*>(p);
}

// write-through 16B store (out buffer only; never re-read on device)
static __device__ __forceinline__ void store_wt16(void* p, f32x4 v) {
  asm volatile("global_store_dwordx4 %0, %1, off sc0 sc1" :: "v"(p), "v"(v) : "memory");
}

static __device__ __forceinline__ int xcc_id() {
  int v;
  asm volatile("s_getreg_b32 %0, hwreg(HW_REG_XCC_ID)" : "=s"(v));
  return v & 7;
}

__global__ void convert_x_kernel(const float* __restrict__ x,
                                 unsigned short* __restrict__ xb, int n4) {
  int i = blockIdx.x * blockDim.x + threadIdx.x;
  int stride = gridDim.x * blockDim.x;
  for (; i < n4; i += stride) {
    float4 v = reinterpret_cast<const float4*>(x)[i];
    ushort4 o;
    o.x = f2bf(v.x); o.y = f2bf(v.y); o.z = f2bf(v.z); o.w = f2bf(v.w);
    reinterpret_cast<ushort4*>(xb)[i] = o;
  }
}

__global__ void init_h_kernel(const float* __restrict__ h,
                              unsigned short* __restrict__ h0r,
                              unsigned short* __restrict__ h1r) {
  int i = blockIdx.x * blockDim.x + threadIdx.x;  // 0..65535
  h0r[(size_t)(RING - 1) * BM + i] = f2bf(h[i]);       // l0 t=0 reads rs=RING-1
  h1r[(size_t)(RING - 1) * BM + i] = f2bf(h[BM + i]);  // l1 t=0 reads rs=RING-1
}

// bar 64B slots: leaf g0:0-15, g1:16-31; root 32+g; rel 34+g*8+xcd;
// relB 50+g*8+xcd; claim 66+g*8+xcd; prog 82+g.
__global__ __launch_bounds__(1024, 4) void lstm_persistent(
    const unsigned short* __restrict__ xb,   // [B][T][N] bf16 (cached)
    const float* __restrict__ c_in,          // [L][B][M]
    const float* __restrict__ Wx,            // [L][4M][N]
    const float* __restrict__ Wh,            // [L][4M][M]
    const float* __restrict__ bias,          // [L][4M]
    float* __restrict__ out,                 // outs | h_last | c_last
    unsigned short* __restrict__ h0r,        // [RING][B][M] bf16
    unsigned short* __restrict__ h1r,        // [RING][B][M] bf16
    int* bar) {
  __shared__ short8 sW[2][2][32][64];  // [mat X/H][mg][kt][lane] 128 KiB
  __shared__ f32x4 red1[12][64];       // mg0 partials
  __shared__ f32x4 red2[12][64];       // mg1 partials

  const int cu = blockIdx.x;
  const int tid = threadIdx.x;
  const int lane = tid & 63;
  const int w = tid >> 6;        // 0..15
  const int g = cu & 1;          // layer group
  const int cuL = cu >> 1;       // 0..127 within group
  const int src = w >> 3;        // 0: A-input, 1: R-input
  const int kh = (w >> 2) & 1;
  const int bt = w & 3;
  const int q = lane >> 4;
  const int bl = lane & 15;
  const int bg = bt * 16 + bl;
  const int mbase = cuL * 8;
  const int xcd = xcc_id();
  const bool owner = (w < 4);
  const bool toucher = (g == 0 && w >= 4 && w < 8);

  unsigned short* hr_own = g ? h1r : h0r;

  // ---- stage weights (once): this layer's Wx + Wh for 32 gate rows ----
  {
    const float* baseX = Wx + (size_t)g * G4M * N_SZ;
    const float* baseH = Wh + (size_t)g * G4M * M_SZ;
#pragma unroll
    for (int mat = 0; mat < 2; ++mat) {
      const float* base = mat ? baseH : baseX;
#pragma unroll
      for (int mg = 0; mg < 2; ++mg) {
        for (int s = tid; s < 32 * 64; s += 1024) {
          int kt = s >> 6, ls = s & 63;
          int r = ls & 15;
          int k0 = kt * 32 + (ls >> 4) * 8;
          int j = (r >> 2) * 1024 + mbase + mg * 4 + (r & 3);
          const float* srcp = base + (size_t)j * 1024 + k0;
          float4 a = reinterpret_cast<const float4*>(srcp)[0];
          float4 b2 = reinterpret_cast<const float4*>(srcp)[1];
          short8 wv;
          wv[0] = (short)f2bf(a.x); wv[1] = (short)f2bf(a.y);
          wv[2] = (short)f2bf(a.z); wv[3] = (short)f2bf(a.w);
          wv[4] = (short)f2bf(b2.x); wv[5] = (short)f2bf(b2.y);
          wv[6] = (short)f2bf(b2.z); wv[7] = (short)f2bf(b2.w);
          sW[mat][mg][kt][ls] = wv;
        }
      }
    }
  }

  // ---- per-(group,XCD) leader election (once) ----
  bool leader = false;
  if (tid == 0) {
    int expected = 0;
    leader = __hip_atomic_compare_exchange_strong(
        bar + 16 * (66 + g * 8 + xcd), &expected, cu + 1, __ATOMIC_RELAXED,
        __ATOMIC_RELAXED, __HIP_MEMORY_SCOPE_AGENT);
  }
  __syncthreads();

  // ---- owner state: c and bias for mg0, mg1 ----
  float c_st[2][4] = {{0.f,0.f,0.f,0.f},{0.f,0.f,0.f,0.f}};
  float bs[2][4] = {{0.f,0.f,0.f,0.f},{0.f,0.f,0.f,0.f}};
  if (owner) {
#pragma unroll
    for (int mg = 0; mg < 2; ++mg)
#pragma unroll
      for (int e = 0; e < 4; ++e) {
        c_st[mg][e] = c_in[g * BM + bg * M_SZ + mbase + mg * 4 + e];
        bs[mg][e] = bias[g * G4M + q * 1024 + mbase + mg * 4 + e];
      }
  }

  const int ko = q * 8;
  const int ktb = kh * 16;
  int* prog0 = bar + 16 * 82;
  int* prog1 = bar + 16 * 83;

  // layer1: wait for layer0's step 0 before starting
  if (g == 1 && tid == 0) {
    int guard = 0;
    while (__hip_atomic_load(prog0, __ATOMIC_RELAXED, __HIP_MEMORY_SCOPE_AGENT) < 1) {
      __builtin_amdgcn_s_sleep(1);
      if (++guard > (1 << 22)) break;
    }
  }
  __syncthreads();

  for (int k = 0; k < T_STEPS; ++k) {
    const int rs = (k + RING - 1) & (RING - 1);
    const int wslot = k & (RING - 1);

    // ---- input pointer for this wave ----
    const unsigned short* ip;
    if (src == 0) {
      ip = g ? (h0r + (size_t)wslot * BM + (size_t)bg * M_SZ)         // h0[t=k]
             : (xb + ((size_t)bg * T_STEPS + k) * N_SZ);              // x[t=k]
    } else {
      ip = hr_own + (size_t)rs * BM + (size_t)bg * M_SZ;              // h[t-1]
    }

    f32x4 acc0 = { 0.f, 0.f, 0.f, 0.f };
    f32x4 acc1 = { 0.f, 0.f, 0.f, 0.f };
    if (owner) {
#pragma unroll
      for (int e = 0; e < 4; ++e) { acc0[e] = bs[0][e]; acc1[e] = bs[1][e]; }
    }

    // ---- 16 fragment loads, all in flight; 32 MFMAs (mg0 + mg1) ----
    short8 f[16];
#pragma unroll
    for (int j = 0; j < 16; ++j) f[j] = ld16(ip + (ktb + j) * 32 + ko);
    asm volatile("" ::
      "v"(f[0]), "v"(f[1]), "v"(f[2]), "v"(f[3]),
      "v"(f[4]), "v"(f[5]), "v"(f[6]), "v"(f[7]),
      "v"(f[8]), "v"(f[9]), "v"(f[10]), "v"(f[11]),
      "v"(f[12]), "v"(f[13]), "v"(f[14]), "v"(f[15]));
    __builtin_amdgcn_sched_barrier(0);
#pragma unroll
    for (int j = 0; j < 16; ++j) {
      int kt = ktb + j;
      acc0 = __builtin_amdgcn_mfma_f32_16x16x32_bf16(sW[src][0][kt][lane], f[j], acc0, 0, 0, 0);
      acc1 = __builtin_amdgcn_mfma_f32_16x16x32_bf16(sW[src][1][kt][lane], f[j], acc1, 0, 0, 0);
    }

    // ---- reduce partials (writers: w4-15) ----
    if (!owner) {
      int idx = (w >> 2) - 1;          // 0,1,2
      red1[idx * 4 + bt][lane] = acc0;
      red2[idx * 4 + bt][lane] = acc1;
    }
    asm volatile("s_waitcnt lgkmcnt(0)" ::: "memory");
    __builtin_amdgcn_s_barrier();
    __builtin_amdgcn_sched_barrier(0);

    // ---- owners: pointwise for mg0, mg1 ----
    if (owner) {
      f32x4 tot[2];
      tot[0] = acc0 + red1[bt][lane] + red1[4 + bt][lane] + red1[8 + bt][lane];
      tot[1] = acc1 + red2[bt][lane] + red2[4 + bt][lane] + red2[8 + bt][lane];
      float hv[2][4];
#pragma unroll
      for (int mg = 0; mg < 2; ++mg) {
#pragma unroll
        for (int e = 0; e < 4; ++e) {
          float ge_i = __shfl(tot[mg][e], bl);
          float ge_f = __shfl(tot[mg][e], bl + 16);
          float ge_g = __shfl(tot[mg][e], bl + 32);
          float ge_o = __shfl(tot[mg][e], bl + 48);
          float gi = sigf(ge_i), gf = sigf(ge_f);
          float gg = tanhfast(ge_g), go = sigf(ge_o);
          float c = gf * c_st[mg][e] + gi * gg;
          c_st[mg][e] = c;
          hv[mg][e] = go * tanhfast(c);
        }
      }
      if (q == 0) {
#pragma unroll
        for (int mg = 0; mg < 2; ++mg) {
          unsigned short* hdst = hr_own + (size_t)wslot * BM +
                                 (size_t)bg * M_SZ + mbase + mg * 4;
          unsigned long long hb =
              (unsigned long long)f2bf(hv[mg][0]) |
              ((unsigned long long)f2bf(hv[mg][1]) << 16) |
              ((unsigned long long)f2bf(hv[mg][2]) << 32) |
              ((unsigned long long)f2bf(hv[mg][3]) << 48);
          __hip_atomic_store((unsigned long long*)hdst, hb, __ATOMIC_RELAXED,
                             __HIP_MEMORY_SCOPE_AGENT);
          if (g == 1) {
            f32x4 ov = { hv[mg][0], hv[mg][1], hv[mg][2], hv[mg][3] };
            store_wt16(out + ((size_t)bg * T_STEPS + k) * M_SZ + mbase + mg * 4, ov);
          }
          if (k == T_STEPS - 1) {
            f32x4 hf = { hv[mg][0], hv[mg][1], hv[mg][2], hv[mg][3] };
            f32x4 cf = { c_st[mg][0], c_st[mg][1], c_st[mg][2], c_st[mg][3] };
            store_wt16(out + OUTS + (size_t)g * BM + (size_t)bg * M_SZ + mbase + mg * 4, hf);
            store_wt16(out + OUTS + 2 * (size_t)BM + (size_t)g * BM +
                       (size_t)bg * M_SZ + mbase + mg * 4, cf);
          }
        }
      }
    }

    // ---- g0 touch waves: warm L2 with x[t+1] (one dword per lane, sliced) ----
    if (toucher && (k + 1 < T_STEPS)) {
      const int idx = (w - 4) * 64 + lane;           // 0..255
      const int b = (cuL & 3) * 16 + (idx >> 4);     // 16 b-rows per CU slice
      const int line = idx & 15;                     // 16 x 128B lines per row
      const unsigned short* tp =
          xb + ((size_t)b * T_STEPS + (k + 1)) * N_SZ + line * 64;
      int tdummy;
      asm volatile("global_load_dword %0, %1, off" : "=v"(tdummy) : "v"(tp));
      asm volatile("" :: "v"(tdummy));
    }

    // ---- group barrier + progress publication + cross-group gates ----
    {
      const int target = k + 1;
      const bool invstep = ((k & (RING - 1)) == (RING - 1));
      // drains: owners must retire their h store before arrival; g1's HBM
      // out-store may keep flying (vmcnt(1), in-order retirement). Touch
      // waves drain their single touch load (WAW safety for next step).
      if (owner) {
        if (k == T_STEPS - 1 || g == 0)
          asm volatile("s_waitcnt vmcnt(0)" ::: "memory");
        else
          asm volatile("s_waitcnt vmcnt(1)" ::: "memory");
      } else if (toucher) {
        asm volatile("s_waitcnt vmcnt(0)" ::: "memory");
      }
      __builtin_amdgcn_s_barrier();          // group's h stores visible at LLC
      if (tid == 0) {
        int* leaf = bar + 16 * (g * 16 + (cuL & 15));   // 8 WGs per leaf
        int* root = bar + 16 * (32 + g);
        int prev = __hip_atomic_fetch_add(leaf, 1, __ATOMIC_RELAXED, __HIP_MEMORY_SCOPE_AGENT);
        if ((prev & 7) == 7) {
          int pr2 = __hip_atomic_fetch_add(root, 1, __ATOMIC_RELAXED, __HIP_MEMORY_SCOPE_AGENT);
          if ((pr2 & 15) == 15) {
            // last arriver of this group: publish progress + release
            __hip_atomic_store(bar + 16 * (82 + g), target, __ATOMIC_RELAXED,
                               __HIP_MEMORY_SCOPE_AGENT);
#pragma unroll
            for (int xx = 0; xx < 8; ++xx)
              __hip_atomic_store(bar + 16 * (34 + g * 8 + xx), target,
                                 __ATOMIC_RELAXED, __HIP_MEMORY_SCOPE_AGENT);
          }
        }
        int guard = 0;
        int* rel  = bar + 16 * (34 + g * 8 + xcd);
        int* relB = bar + 16 * (50 + g * 8 + xcd);
        while (__hip_atomic_load(rel, __ATOMIC_RELAXED, __HIP_MEMORY_SCOPE_AGENT) < target) {
          __builtin_amdgcn_s_sleep(1);
          if (++guard > (1 << 22)) break;    // failsafe: wrong answer, not hang
        }
        // cross-group gates for the UPCOMING step (k+1)
        if (g == 1 && k + 1 < T_STEPS) {
          int need = (k + 2 < T_STEPS + 1) ? (k + 2) : T_STEPS;
          guard = 0;
          while (__hip_atomic_load(prog0, __ATOMIC_RELAXED, __HIP_MEMORY_SCOPE_AGENT) < need) {
            __builtin_amdgcn_s_sleep(1);
            if (++guard > (1 << 22)) break;
          }
        } else if (g == 0 && k + 1 >= RING && k + 1 < T_STEPS) {
          int need = k - (RING - 2);           // l1 must have consumed old slot
          guard = 0;
          while (__hip_atomic_load(prog1, __ATOMIC_RELAXED, __HIP_MEMORY_SCOPE_AGENT) < need) {
            __builtin_amdgcn_s_sleep(1);
            if (++guard > (1 << 22)) break;
          }
        }
        if (invstep) {
          if (leader) {
            asm volatile("buffer_inv sc0 sc1\n\ts_waitcnt vmcnt(0)" ::: "memory");
            __hip_atomic_store(relB, target, __ATOMIC_RELAXED, __HIP_MEMORY_SCOPE_AGENT);
          } else {
            guard = 0;
            while (__hip_atomic_load(relB, __ATOMIC_RELAXED, __HIP_MEMORY_SCOPE_AGENT) < target) {
              __builtin_amdgcn_s_sleep(1);
              if (++guard > (1 << 22)) break;
            }
            asm volatile("buffer_inv sc0\n\ts_waitcnt vmcnt(0)" ::: "memory");
          }
        }
      }
      __builtin_amdgcn_s_barrier();          // release within WG
      __builtin_amdgcn_sched_barrier(0);
    }
  }
}

extern "C" void kernel_launch(void* const* d_in, const int* in_sizes, int n_in,
                              void* d_out, int out_size, void* d_ws, size_t ws_size,
                              hipStream_t stream) {
  (void)in_sizes; (void)n_in; (void)out_size; (void)ws_size;
  const float* x  = (const float*)d_in[0];
  const float* h  = (const float*)d_in[1];
  const float* c  = (const float*)d_in[2];
  const float* Wx = (const float*)d_in[3];
  const float* Wh = (const float*)d_in[4];
  const float* b  = (const float*)d_in[5];
  float* out = (float*)d_out;

  char* ws = (char*)d_ws;
  int* bar = (int*)ws;                              // counter cachelines (<8KB)
  unsigned short* h0r = (unsigned short*)(ws + 8192);
  unsigned short* h1r = (unsigned short*)(ws + 8192 + (size_t)RING * BM * 2);
  unsigned short* xb  = (unsigned short*)(ws + 8192 + (size_t)RING * BM * 4);
  // ws use: 8 KB + 2*8 MB (h rings) + 32 MB (xb) ~= 48 MB

  (void)hipMemsetAsync(ws, 0, 8192, stream);
  convert_x_kernel<<<2048, 256, 0, stream>>>(x, xb, (B_SZ * T_STEPS * N_SZ) / 4);
  init_h_kernel<<<256, 256, 0, stream>>>(h, h0r, h1r);
  lstm_persistent<<<256, 1024, 0, stream>>>(xb, c, Wx, Wh, b, out, h0r, h1r, bar);
}